// Round 11
// baseline (156.143 us; speedup 1.0000x reference)
//
#include <hip/hip_runtime.h>

#define TT 2048
#define DD 1024
#define NHH 8
#define DKK 128
// softmax in log2 domain: v_exp_f32 is natively 2^x
#define SCALE2 0.1275174724f          /* (1/sqrt(128)) * log2(e) */

typedef __attribute__((ext_vector_type(8)))  short short8;
typedef __attribute__((ext_vector_type(4)))  short short4v;
typedef __attribute__((ext_vector_type(4)))  float float4v;
typedef __attribute__((ext_vector_type(16))) float float16v;
typedef __attribute__((ext_vector_type(4)))  int   int4v;

__device__ __forceinline__ short f2bf(float f) {
  union { float f; unsigned u; } v; v.f = f;
  unsigned r = v.u + 0x7FFFu + ((v.u >> 16) & 1u);
  return (short)(r >> 16);
}
__device__ __forceinline__ unsigned cvtpk(float lo, float hi) {
  unsigned r;
  asm("v_cvt_pk_bf16_f32 %0, %1, %2" : "=v"(r) : "v"(lo), "v"(hi));
  return r;
}
// pairwise exchange lane l <-> l^32 (VALU pipe, not LDS)
__device__ __forceinline__ float xhalf_add(float x) {
  float y;
  asm("v_mov_b32 %0, %1" : "=v"(y) : "v"(x));
  asm("v_permlane32_swap_b32 %0, %1" : "+v"(x), "+v"(y));
  return x + y;
}
// 16-chunk swizzle for 256B rows
__device__ __forceinline__ int s4(int row) {
  return (row & 7) ^ (((row >> 3) & 3) << 2);
}
// async global->LDS, 16B per lane; lds base is wave-uniform, gsrc per-lane
__device__ __forceinline__ void gl2lds(const void* g, void* l) {
  __builtin_amdgcn_global_load_lds(
      (const __attribute__((address_space(1))) void*)g,
      (__attribute__((address_space(3))) void*)l, 16, 0, 0);
}

// ---- transpose + cast: x (B, D, T) f32 -> xt (B*T, D) bf16 ----
__global__ __launch_bounds__(256) void k_xt(const float* __restrict__ x,
                                            short* __restrict__ xt) {
  __shared__ float tile[32][33];
  int b = blockIdx.z, d0 = blockIdx.y << 5, t0 = blockIdx.x << 5;
  int tx = threadIdx.x & 31, ty = threadIdx.x >> 5;
  const float* xp = x + ((size_t)b * DD + d0) * TT + t0;
#pragma unroll
  for (int yy = 0; yy < 32; yy += 8)
    tile[ty + yy][tx] = xp[(size_t)(ty + yy) * TT + tx];
  __syncthreads();
  short* op = xt + ((size_t)b * TT + t0) * DD + d0;
#pragma unroll
  for (int yy = 0; yy < 32; yy += 8)
    op[(size_t)(ty + yy) * DD + tx] = f2bf(tile[tx][ty + yy]);
}

__global__ void k_cast(const float* __restrict__ w, short* __restrict__ o, int n4) {
  int i = blockIdx.x * 256 + threadIdx.x;
  if (i < n4) {
    float4v v = ((const float4v*)w)[i];
    short4v s;
#pragma unroll
    for (int j = 0; j < 4; ++j) s[j] = f2bf(v[j]);
    ((short4v*)o)[i] = s;
  }
}

// ---- transpose Q: qb (B*T, 1024) bf16 -> qhT (B*1024, T) bf16 ----
__global__ __launch_bounds__(256) void k_qt(const short* __restrict__ qb,
                                            short* __restrict__ qhT) {
  __shared__ short tile[64][65];
  int b = blockIdx.z, n0 = blockIdx.y << 6, t0 = blockIdx.x << 6;
  int tx = threadIdx.x & 63, ty = threadIdx.x >> 6;
  const short* ip = qb + ((size_t)(b * TT + t0)) * DD + n0;
#pragma unroll
  for (int yy = 0; yy < 64; yy += 4)
    tile[ty + yy][tx] = ip[(size_t)(ty + yy) * DD + tx];
  __syncthreads();
  short* op = qhT + ((size_t)(b * DD + n0)) * TT + t0;
#pragma unroll
  for (int yy = 0; yy < 64; yy += 4)
    op[(size_t)(ty + yy) * TT + tx] = tile[tx][ty + yy];
}

// ---- GEMM: C = A(M x 1024) * Bt(N x 1024)^T  — m97 recipe ----
// Linear LDS [128][64], global_load_lds w=16, pre-swizzled source (^row&7).
template <int EPI>
__global__ __launch_bounds__(256) void k_gemm(const short* __restrict__ A,
                                              const short* __restrict__ Bt,
                                              void* __restrict__ Cout) {
  __shared__ __align__(16) short As[128 * 64];
  __shared__ __align__(16) short Bs[128 * 64];
  const int K = 1024;
  int tm = blockIdx.x * 128, tn = blockIdx.y * 128;
  int tid = threadIdx.x, lane = tid & 63, w = tid >> 6;
  int wm = (w >> 1) * 64, wn = (w & 1) * 64;
  int ql = lane & 15, g = lane >> 4;

  // staging map: chunk cg = w*4+c (1KB each); row = cg*8 + (lane>>3);
  // source col-chunk = (lane&7) ^ (row&7)  [so LDS[r][cc] = M[r][cc^(r&7)]]
  int srow[4], scol[4];
#pragma unroll
  for (int c = 0; c < 4; ++c) {
    int cg = w * 4 + c;
    int r = cg * 8 + (lane >> 3);
    srow[c] = r;
    scol[c] = ((lane & 7) ^ (r & 7)) * 8;
  }

  float4v acc[4][4];
#pragma unroll
  for (int mt = 0; mt < 4; ++mt)
#pragma unroll
    for (int nt = 0; nt < 4; ++nt) acc[mt][nt] = (float4v){0.f, 0.f, 0.f, 0.f};

  for (int k0 = 0; k0 < K; k0 += 64) {
    __syncthreads();
#pragma unroll
    for (int c = 0; c < 4; ++c) {
      int cg = w * 4 + c;
      gl2lds(A + (size_t)(tm + srow[c]) * K + k0 + scol[c], As + cg * 512);
      gl2lds(Bt + (size_t)(tn + srow[c]) * K + k0 + scol[c], Bs + cg * 512);
    }
    __syncthreads();
#pragma unroll
    for (int k4 = 0; k4 < 2; ++k4) {
      short8 af[4], bfr[4];
#pragma unroll
      for (int mt = 0; mt < 4; ++mt) {
        int row = wm + mt * 16 + ql;
        af[mt] = *(const short8*)(As + row * 64 + (((k4 * 4 + g) ^ (ql & 7)) * 8));
      }
#pragma unroll
      for (int nt = 0; nt < 4; ++nt) {
        int row = wn + nt * 16 + ql;
        bfr[nt] = *(const short8*)(Bs + row * 64 + (((k4 * 4 + g) ^ (ql & 7)) * 8));
      }
#pragma unroll
      for (int mt = 0; mt < 4; ++mt)
#pragma unroll
        for (int nt = 0; nt < 4; ++nt)
          acc[mt][nt] = __builtin_amdgcn_mfma_f32_16x16x32_bf16(af[mt], bfr[nt],
                                                                acc[mt][nt], 0, 0, 0);
    }
  }

#pragma unroll
  for (int mt = 0; mt < 4; ++mt)
#pragma unroll
    for (int nt = 0; nt < 4; ++nt)
#pragma unroll
      for (int r = 0; r < 4; ++r) {
        int m = tm + wm + mt * 16 + g * 4 + r;
        int n = tn + wn + nt * 16 + ql;
        float v = acc[mt][nt][r];
        if (EPI == 0) {
          ((short*)Cout)[(size_t)m * 1024 + n] = f2bf(v);
        } else {
          int b = n >> 11, t = n & 2047;
          ((float*)Cout)[((size_t)b * 1024 + m) * 2048 + t] = v;
        }
      }
}

// ---- fused masked self-attention, flash-style, 32x32 MFMA ----
// grid (T/128, B*NH), block 256 = 4 waves x 32 q-rows. KVBLK=64.
// Mask rides an extra k=16 MFMA; SCALE2*rm folded into qf; no max-tracking.
// Staging via global_load_lds (linear dest, pre-swizzled source), dbuf.
__global__ __launch_bounds__(256, 2) void k_attn(const short* __restrict__ q,
                                                 const short* __restrict__ qhT,
                                                 const float* __restrict__ mask,
                                                 short* __restrict__ ctx) {
  __shared__ __align__(16) short Ks[2][64 * 128];   // LDS[r][cc]=K[r][cc^s4(r)]
  __shared__ __align__(16) short Vt[2][128 * 64];   // LDS[d][cc]=VT[d][cc^(d&7)]
  __shared__ __align__(16) short Kx[2][64 * 16];    // ext: elem0 = mask?0:-1e30

  int qt = blockIdx.x, bh = blockIdx.y;
  int b = bh >> 3, h = bh & 7;
  int tid = threadIdx.x, lane = tid & 63, w = tid >> 6;
  int ql32 = lane & 31, hi = lane >> 5;
  int csw = s4(ql32);        // K-frag chunk swizzle
  int vsw = ql32 & 7;        // V-frag chunk swizzle
  short negbig = f2bf(-1e30f);

  int qrow = qt * 128 + w * 32 + ql32;
  const short* qp = q + ((size_t)(b * TT + qrow)) * DD + h * DKK;
  short8 qf[8];
#pragma unroll
  for (int kc8 = 0; kc8 < 8; ++kc8)
    qf[kc8] = *(const short8*)(qp + kc8 * 16 + hi * 8);
  float rm = mask[(size_t)b * TT + qrow];

  // fold SCALE2*rm into qf (once; K/V stay raw)
  float qs = SCALE2 * rm;
#pragma unroll
  for (int kc8 = 0; kc8 < 8; ++kc8) {
    union { short8 s; unsigned u[4]; } a;
    a.s = qf[kc8];
#pragma unroll
    for (int j = 0; j < 4; ++j) {
      union { unsigned u; float f; } lo, hh;
      lo.u = a.u[j] << 16;
      hh.u = a.u[j] & 0xFFFF0000u;
      a.u[j] = cvtpk(lo.f * qs, hh.f * qs);
    }
    qf[kc8] = a.s;
  }
  // ext B-frag: B[k=0][col=own q] = rm  (bf16 of 0.0/1.0)
  short8 bext = (short8)0;
  if (hi == 0) bext[0] = (rm != 0.f) ? (short)0x3F80 : (short)0;

  // gload_lds staging maps (per wave: 4 K-chunks + 4 V-chunks of 1KB)
  // K: chunk cg -> rows cg*4+(lane>>4), col-chunk (lane&15)^s4(r)
  // V: chunk cg -> rows cg*8+(lane>>3), col-chunk (lane&7)^(r&7)
  int krow[4], kcol[4], vrow[4], vcol[4];
#pragma unroll
  for (int c = 0; c < 4; ++c) {
    int cg = w * 4 + c;
    int kr = cg * 4 + (lane >> 4);
    krow[c] = kr;
    kcol[c] = (((lane & 15) ^ s4(kr)) * 8);
    int vr = cg * 8 + (lane >> 3);
    vrow[c] = vr;
    vcol[c] = (((lane & 7) ^ (vr & 7)) * 8);
  }
  const short* kbase_g = q + ((size_t)b * TT) * DD + h * DKK;
  const short* vbase_g = qhT + ((size_t)(b * DD + h * DKK)) * TT;

  // prologue: issue tile-0 DMA into buf 0; zero Kx tails; tile-0 mask row
  float mreg = mask[(size_t)b * TT + lane];
#pragma unroll
  for (int c = 0; c < 4; ++c) {
    int cg = w * 4 + c;
    gl2lds(kbase_g + (size_t)krow[c] * DD + kcol[c], Ks[0] + cg * 512);
    gl2lds(vbase_g + (size_t)vrow[c] * TT + vcol[c], Vt[0] + cg * 512);
  }
  if (tid < 128) {
    short8 z = (short8)0;
    if (tid < 64) z[0] = (mreg != 0.f) ? (short)0 : negbig;
    *(short8*)(&Kx[0][0] + tid * 16) = z;
    *(short8*)(&Kx[0][0] + tid * 16 + 8) = (short8)0;
  }

  float l_run = 0.f;
  float16v o[4];
#pragma unroll
  for (int nt = 0; nt < 4; ++nt)
#pragma unroll
    for (int r = 0; r < 16; ++r) o[nt][r] = 0.f;

  for (int kt = 0; kt < 32; ++kt) {
    int cur = kt & 1;
    const short* ksb = Ks[cur];
    const short* vtb = Vt[cur];
    const short* kxb = Kx[cur];
    short* ksn = Ks[cur ^ 1];
    short* vtn = Vt[cur ^ 1];
    short* kxn = Kx[cur ^ 1];

    __syncthreads();   // buf[cur] DMA complete (vmcnt drain); buf[cur^1] free

    // issue next-tile DMA into the other buffer (hides under compute)
    if (kt < 31) {
      int kb0n = (kt + 1) * 64;
#pragma unroll
      for (int c = 0; c < 4; ++c) {
        int cg = w * 4 + c;
        gl2lds(kbase_g + (size_t)(kb0n + krow[c]) * DD + kcol[c], ksn + cg * 512);
        gl2lds(vbase_g + (size_t)vrow[c] * TT + kb0n + vcol[c], vtn + cg * 512);
      }
      mreg = mask[(size_t)b * TT + kb0n + lane];
    }

    // ---- S^T = K * Q^T (+ mask-bias ext MFMA). C col = q = ql32 ----
    float16v st0, st1;
#pragma unroll
    for (int r = 0; r < 16; ++r) { st0[r] = 0.f; st1[r] = 0.f; }
    __builtin_amdgcn_s_setprio(1);
    {
      short8 ax0 = *(const short8*)(kxb + ql32 * 16 + hi * 8);
      short8 ax1 = *(const short8*)(kxb + (32 + ql32) * 16 + hi * 8);
      st0 = __builtin_amdgcn_mfma_f32_32x32x16_bf16(ax0, bext, st0, 0, 0, 0);
      st1 = __builtin_amdgcn_mfma_f32_32x32x16_bf16(ax1, bext, st1, 0, 0, 0);
    }
#pragma unroll
    for (int kc8 = 0; kc8 < 8; ++kc8) {
      int csk = ((kc8 * 2 + hi) ^ csw) * 8;
      short8 kf0 = *(const short8*)(ksb + ql32 * 128 + csk);
      short8 kf1 = *(const short8*)(ksb + (32 + ql32) * 128 + csk);
      st0 = __builtin_amdgcn_mfma_f32_32x32x16_bf16(kf0, qf[kc8], st0, 0, 0, 0);
      st1 = __builtin_amdgcn_mfma_f32_32x32x16_bf16(kf1, qf[kc8], st1, 0, 0, 0);
    }
    __builtin_amdgcn_s_setprio(0);

    // ---- softmax core: p = exp2(logit), accumulate denominator ----
    float tsum = 0.f;
#pragma unroll
    for (int r = 0; r < 16; ++r) {
      float p0 = __builtin_amdgcn_exp2f(st0[r]);
      float p1 = __builtin_amdgcn_exp2f(st1[r]);
      st0[r] = p0; st1[r] = p1;
      tsum += p0 + p1;
    }
    l_run += xhalf_add(tsum);

    // ---- P^T B-frags in-register: cvt_pk + permlane32_swap (T12) ----
    short8 pa[4];
#pragma unroll
    for (int kc = 0; kc < 4; ++kc) {
      int a0 = 2 * (kc & 1);
      unsigned x0, x1, y0, y1;
      if (kc < 2) {
        x0 = cvtpk(st0[4 * a0 + 0], st0[4 * a0 + 1]);
        x1 = cvtpk(st0[4 * a0 + 2], st0[4 * a0 + 3]);
        y0 = cvtpk(st0[4 * a0 + 4], st0[4 * a0 + 5]);
        y1 = cvtpk(st0[4 * a0 + 6], st0[4 * a0 + 7]);
      } else {
        x0 = cvtpk(st1[4 * a0 + 0], st1[4 * a0 + 1]);
        x1 = cvtpk(st1[4 * a0 + 2], st1[4 * a0 + 3]);
        y0 = cvtpk(st1[4 * a0 + 4], st1[4 * a0 + 5]);
        y1 = cvtpk(st1[4 * a0 + 6], st1[4 * a0 + 7]);
      }
      asm("v_permlane32_swap_b32 %0, %1" : "+v"(x0), "+v"(y0));
      asm("v_permlane32_swap_b32 %0, %1" : "+v"(x1), "+v"(y1));
      union { unsigned u[4]; short8 s8; } pu;
      pu.u[0] = x0; pu.u[1] = x1; pu.u[2] = y0; pu.u[3] = y1;
      pa[kc] = pu.s8;
    }

    // ---- O^T += V^T * P^T ----
    __builtin_amdgcn_s_setprio(1);
#pragma unroll
    for (int nt = 0; nt < 4; ++nt) {
      int row = nt * 32 + ql32;
#pragma unroll
      for (int kc = 0; kc < 4; ++kc) {
        short8 vf = *(const short8*)(vtb + row * 64 + (((kc * 2 + hi) ^ vsw) * 8));
        o[nt] = __builtin_amdgcn_mfma_f32_32x32x16_bf16(vf, pa[kc], o[nt], 0, 0, 0);
      }
    }
    __builtin_amdgcn_s_setprio(0);

    // ---- Kx for next tile (mreg has landed by dependency wait) ----
    if (kt < 31 && tid < 64) {
      unsigned word = (mreg != 0.f) ? 0u : (unsigned)(unsigned short)negbig;
      *(unsigned*)(kxn + tid * 16) = word;   // elems 0,1 (elem1=0)
    }
  }

  // ---- normalize and write ctx: lane owns q-row, d = nt*32+8a+4hi+{0..3} ----
  float il = 1.0f / l_run;
  short* cp = ctx + ((size_t)(b * TT + qrow)) * DD + h * DKK;
#pragma unroll
  for (int nt = 0; nt < 4; ++nt)
#pragma unroll
    for (int a = 0; a < 4; ++a) {
      short4v sv;
#pragma unroll
      for (int j = 0; j < 4; ++j) sv[j] = f2bf(o[nt][4 * a + j] * il);
      *(short4v*)(cp + nt * 32 + 8 * a + 4 * hi) = sv;
    }
}

extern "C" void kernel_launch(void* const* d_in, const int* in_sizes, int n_in,
                              void* d_out, int out_size, void* d_ws, size_t ws_size,
                              hipStream_t stream) {
  const float* x    = (const float*)d_in[0];
  const float* mask = (const float*)d_in[1];
  const float* Wq   = (const float*)d_in[2];
  const float* Wo   = (const float*)d_in[3];
  char* ws = (char*)d_ws;
  short* xt  = (short*)(ws);                              // 16 MB (reused as qhT)
  short* wqb = (short*)(ws + (size_t)16 * 1024 * 1024);
  short* wob = (short*)(ws + (size_t)18 * 1024 * 1024);
  short* qb  = (short*)(ws + (size_t)20 * 1024 * 1024);
  short* ctx = (short*)(ws + (size_t)36 * 1024 * 1024);
  short* qhT = xt;   // xt dead after k_gemm<0>

  k_xt<<<dim3(64, 32, 4), 256, 0, stream>>>(x, xt);
  k_cast<<<1024, 256, 0, stream>>>(Wq, wqb, 262144);
  k_cast<<<1024, 256, 0, stream>>>(Wo, wob, 262144);
  k_gemm<0><<<dim3(64, 8), 256, 0, stream>>>(xt, wqb, qb);
  k_qt<<<dim3(32, 16, 4), 256, 0, stream>>>(qb, qhT);
  k_attn<<<dim3(16, 32), 256, 0, stream>>>(qb, qhT, mask, ctx);
  k_gemm<1><<<dim3(8, 64), 256, 0, stream>>>(wob, ctx, d_out);
}

// Round 12
// 148.224 us; speedup vs baseline: 1.0534x; 1.0534x over previous
//
#include <hip/hip_runtime.h>

#define TT 2048
#define DD 1024
#define NHH 8
#define DKK 128
// softmax in log2 domain: v_exp_f32 is natively 2^x
#define SCALE2 0.1275174724f          /* (1/sqrt(128)) * log2(e) */

typedef __attribute__((ext_vector_type(8)))  short short8;
typedef __attribute__((ext_vector_type(4)))  short short4v;
typedef __attribute__((ext_vector_type(4)))  float float4v;
typedef __attribute__((ext_vector_type(16))) float float16v;
typedef __attribute__((ext_vector_type(4)))  int   int4v;

__device__ __forceinline__ short f2bf(float f) {
  union { float f; unsigned u; } v; v.f = f;
  unsigned r = v.u + 0x7FFFu + ((v.u >> 16) & 1u);
  return (short)(r >> 16);
}
__device__ __forceinline__ unsigned cvtpk(float lo, float hi) {
  unsigned r;
  asm("v_cvt_pk_bf16_f32 %0, %1, %2" : "=v"(r) : "v"(lo), "v"(hi));
  return r;
}
// pairwise exchange lane l <-> l^32 (VALU pipe, not LDS)
__device__ __forceinline__ float xhalf_add(float x) {
  float y;
  asm("v_mov_b32 %0, %1" : "=v"(y) : "v"(x));
  asm("v_permlane32_swap_b32 %0, %1" : "+v"(x), "+v"(y));
  return x + y;
}
// 16-chunk swizzle for 256B rows
__device__ __forceinline__ int s4(int row) {
  return (row & 7) ^ (((row >> 3) & 3) << 2);
}
// async global->LDS, 16B per lane; lds base is wave-uniform, gsrc per-lane
__device__ __forceinline__ void gl2lds(const void* g, void* l) {
  __builtin_amdgcn_global_load_lds(
      (const __attribute__((address_space(1))) void*)g,
      (__attribute__((address_space(3))) void*)l, 16, 0, 0);
}

// ---- transpose + cast: x (B, D, T) f32 -> xt (B*T, D) bf16 ----
__global__ __launch_bounds__(256) void k_xt(const float* __restrict__ x,
                                            short* __restrict__ xt) {
  __shared__ float tile[32][33];
  int b = blockIdx.z, d0 = blockIdx.y << 5, t0 = blockIdx.x << 5;
  int tx = threadIdx.x & 31, ty = threadIdx.x >> 5;
  const float* xp = x + ((size_t)b * DD + d0) * TT + t0;
#pragma unroll
  for (int yy = 0; yy < 32; yy += 8)
    tile[ty + yy][tx] = xp[(size_t)(ty + yy) * TT + tx];
  __syncthreads();
  short* op = xt + ((size_t)b * TT + t0) * DD + d0;
#pragma unroll
  for (int yy = 0; yy < 32; yy += 8)
    op[(size_t)(ty + yy) * DD + tx] = f2bf(tile[tx][ty + yy]);
}

__global__ void k_cast(const float* __restrict__ w, short* __restrict__ o, int n4) {
  int i = blockIdx.x * 256 + threadIdx.x;
  if (i < n4) {
    float4v v = ((const float4v*)w)[i];
    short4v s;
#pragma unroll
    for (int j = 0; j < 4; ++j) s[j] = f2bf(v[j]);
    ((short4v*)o)[i] = s;
  }
}

// ---- transpose Q: qb (B*T, 1024) bf16 -> qhT (B*1024, T) bf16 ----
__global__ __launch_bounds__(256) void k_qt(const short* __restrict__ qb,
                                            short* __restrict__ qhT) {
  __shared__ short tile[64][65];
  int b = blockIdx.z, n0 = blockIdx.y << 6, t0 = blockIdx.x << 6;
  int tx = threadIdx.x & 63, ty = threadIdx.x >> 6;
  const short* ip = qb + ((size_t)(b * TT + t0)) * DD + n0;
#pragma unroll
  for (int yy = 0; yy < 64; yy += 4)
    tile[ty + yy][tx] = ip[(size_t)(ty + yy) * DD + tx];
  __syncthreads();
  short* op = qhT + ((size_t)(b * DD + n0)) * TT + t0;
#pragma unroll
  for (int yy = 0; yy < 64; yy += 4)
    op[(size_t)(ty + yy) * TT + tx] = tile[tx][ty + yy];
}

// ---- GEMM: C = A(M x 1024) * Bt(N x 1024)^T  — m97 recipe (kept from R11) ----
template <int EPI>
__global__ __launch_bounds__(256) void k_gemm(const short* __restrict__ A,
                                              const short* __restrict__ Bt,
                                              void* __restrict__ Cout) {
  __shared__ __align__(16) short As[128 * 64];
  __shared__ __align__(16) short Bs[128 * 64];
  const int K = 1024;
  int tm = blockIdx.x * 128, tn = blockIdx.y * 128;
  int tid = threadIdx.x, lane = tid & 63, w = tid >> 6;
  int wm = (w >> 1) * 64, wn = (w & 1) * 64;
  int ql = lane & 15, g = lane >> 4;

  int srow[4], scol[4];
#pragma unroll
  for (int c = 0; c < 4; ++c) {
    int cg = w * 4 + c;
    int r = cg * 8 + (lane >> 3);
    srow[c] = r;
    scol[c] = ((lane & 7) ^ (r & 7)) * 8;
  }

  float4v acc[4][4];
#pragma unroll
  for (int mt = 0; mt < 4; ++mt)
#pragma unroll
    for (int nt = 0; nt < 4; ++nt) acc[mt][nt] = (float4v){0.f, 0.f, 0.f, 0.f};

  for (int k0 = 0; k0 < K; k0 += 64) {
    __syncthreads();
#pragma unroll
    for (int c = 0; c < 4; ++c) {
      int cg = w * 4 + c;
      gl2lds(A + (size_t)(tm + srow[c]) * K + k0 + scol[c], As + cg * 512);
      gl2lds(Bt + (size_t)(tn + srow[c]) * K + k0 + scol[c], Bs + cg * 512);
    }
    __syncthreads();
#pragma unroll
    for (int k4 = 0; k4 < 2; ++k4) {
      short8 af[4], bfr[4];
#pragma unroll
      for (int mt = 0; mt < 4; ++mt) {
        int row = wm + mt * 16 + ql;
        af[mt] = *(const short8*)(As + row * 64 + (((k4 * 4 + g) ^ (ql & 7)) * 8));
      }
#pragma unroll
      for (int nt = 0; nt < 4; ++nt) {
        int row = wn + nt * 16 + ql;
        bfr[nt] = *(const short8*)(Bs + row * 64 + (((k4 * 4 + g) ^ (ql & 7)) * 8));
      }
#pragma unroll
      for (int mt = 0; mt < 4; ++mt)
#pragma unroll
        for (int nt = 0; nt < 4; ++nt)
          acc[mt][nt] = __builtin_amdgcn_mfma_f32_16x16x32_bf16(af[mt], bfr[nt],
                                                                acc[mt][nt], 0, 0, 0);
    }
  }

#pragma unroll
  for (int mt = 0; mt < 4; ++mt)
#pragma unroll
    for (int nt = 0; nt < 4; ++nt)
#pragma unroll
      for (int r = 0; r < 4; ++r) {
        int m = tm + wm + mt * 16 + g * 4 + r;
        int n = tn + wn + nt * 16 + ql;
        float v = acc[mt][nt][r];
        if (EPI == 0) {
          ((short*)Cout)[(size_t)m * 1024 + n] = f2bf(v);
        } else {
          int b = n >> 11, t = n & 2047;
          ((float*)Cout)[((size_t)b * 1024 + m) * 2048 + t] = v;
        }
      }
}

// ---- fused masked self-attention (R10 version, measured 82.7 us) ----
// grid (T/128, B*NH), block 256 = 4 waves x 32 q-rows. KVBLK=64.
// Mask rides an extra k=16 MFMA; SCALE2*rm folded into qf; no max-tracking.
// Reg-staged prefetch + dbuf LDS (one barrier/iter).
__global__ __launch_bounds__(256, 2) void k_attn(const short* __restrict__ q,
                                                 const short* __restrict__ qhT,
                                                 const float* __restrict__ mask,
                                                 short* __restrict__ ctx) {
  __shared__ __align__(16) short Ks[2][64 * 128];   // [key][d], 256B rows, s4 swizzle
  __shared__ __align__(16) short Vt[2][128 * 64];   // [d][key], 128B rows, &7 swizzle
  __shared__ __align__(16) short Kx[2][64 * 16];    // ext: elem0 = mask?0:-1e30 (bf16)

  int qt = blockIdx.x, bh = blockIdx.y;
  int b = bh >> 3, h = bh & 7;
  int tid = threadIdx.x, lane = tid & 63, w = tid >> 6;
  int ql32 = lane & 31, hi = lane >> 5;
  int csw = s4(ql32);        // K-frag chunk swizzle
  int vsw = ql32 & 7;        // V-frag chunk swizzle
  short negbig = f2bf(-1e30f);

  int qrow = qt * 128 + w * 32 + ql32;
  const short* qp = q + ((size_t)(b * TT + qrow)) * DD + h * DKK;
  short8 qf[8];
#pragma unroll
  for (int kc8 = 0; kc8 < 8; ++kc8)
    qf[kc8] = *(const short8*)(qp + kc8 * 16 + hi * 8);
  float rm = mask[(size_t)b * TT + qrow];

  // fold SCALE2*rm into qf (once; K/V stay raw)
  float qs = SCALE2 * rm;
#pragma unroll
  for (int kc8 = 0; kc8 < 8; ++kc8) {
    union { short8 s; unsigned u[4]; } a;
    a.s = qf[kc8];
#pragma unroll
    for (int j = 0; j < 4; ++j) {
      union { unsigned u; float f; } lo, hh;
      lo.u = a.u[j] << 16;
      hh.u = a.u[j] & 0xFFFF0000u;
      a.u[j] = cvtpk(lo.f * qs, hh.f * qs);
    }
    qf[kc8] = a.s;
  }
  // ext B-frag: B[k=0][col=own q] = rm  (bf16 of 0.0/1.0)
  short8 bext = (short8)0;
  if (hi == 0) bext[0] = (rm != 0.f) ? (short)0x3F80 : (short)0;

  // staging maps
  int oc = tid & 15, r2 = tid >> 4;
  const short* kbase_g = q + ((size_t)b * TT) * DD + h * DKK + oc * 8;
  const short* vbase_g = qhT + ((size_t)(b * DD + h * DKK)) * TT;
  int vd[4], vko[4], vwoff[4];
#pragma unroll
  for (int p = 0; p < 4; ++p) {
    int idx = p * 256 + tid;
    vd[p] = idx >> 3;
    vko[p] = idx & 7;
    vwoff[p] = vd[p] * 64 + ((vko[p] ^ (vd[p] & 7)) * 8);
  }
  int kwoff[2][2];
#pragma unroll
  for (int ps = 0; ps < 2; ++ps) {
    int ra = 2 * r2 + 32 * ps, rb = ra + 1;
    kwoff[ps][0] = ra * 128 + ((oc ^ s4(ra)) * 8);
    kwoff[ps][1] = rb * 128 + ((oc ^ s4(rb)) * 8);
  }

  // prologue: load tile 0 into regs, stage into buf 0
  short8 va[2], vb[2], vv[4];
#pragma unroll
  for (int ps = 0; ps < 2; ++ps) {
    const short* kp = kbase_g + (size_t)(2 * r2 + 32 * ps) * DD;
    va[ps] = *(const short8*)(kp);
    vb[ps] = *(const short8*)(kp + DD);
  }
#pragma unroll
  for (int p = 0; p < 4; ++p)
    vv[p] = *(const short8*)(vbase_g + (size_t)vd[p] * TT + vko[p] * 8);
  float mreg = mask[(size_t)b * TT + lane];

#pragma unroll
  for (int ps = 0; ps < 2; ++ps) {
    *(short8*)(Ks[0] + kwoff[ps][0]) = va[ps];
    *(short8*)(Ks[0] + kwoff[ps][1]) = vb[ps];
  }
#pragma unroll
  for (int p = 0; p < 4; ++p)
    *(short8*)(Vt[0] + vwoff[p]) = vv[p];
  // Kx init: one thread per row (both bufs) -> no race; buf0 gets tile-0 mask
  if (tid < 128) {
    short8 z = (short8)0;
    if (tid < 64) z[0] = (mreg != 0.f) ? (short)0 : negbig;
    *(short8*)(&Kx[0][0] + tid * 16) = z;
    *(short8*)(&Kx[0][0] + tid * 16 + 8) = (short8)0;
  }

  float l_run = 0.f;
  float16v o[4];
#pragma unroll
  for (int nt = 0; nt < 4; ++nt)
#pragma unroll
    for (int r = 0; r < 16; ++r) o[nt][r] = 0.f;

  for (int kt = 0; kt < 32; ++kt) {
    int cur = kt & 1;
    const short* ksb = Ks[cur];
    const short* vtb = Vt[cur];
    const short* kxb = Kx[cur];
    short* ksn = Ks[cur ^ 1];
    short* vtn = Vt[cur ^ 1];
    short* kxn = Kx[cur ^ 1];

    __syncthreads();   // buf[cur] fully staged; buf[cur^1] free to overwrite

    // issue next-tile loads (land during compute below)
    if (kt < 31) {
      int kb0n = (kt + 1) * 64;
      const short* kpn = kbase_g + (size_t)kb0n * DD;
#pragma unroll
      for (int ps = 0; ps < 2; ++ps) {
        const short* kp = kpn + (size_t)(2 * r2 + 32 * ps) * DD;
        va[ps] = *(const short8*)(kp);
        vb[ps] = *(const short8*)(kp + DD);
      }
#pragma unroll
      for (int p = 0; p < 4; ++p)
        vv[p] = *(const short8*)(vbase_g + (size_t)vd[p] * TT + kb0n + vko[p] * 8);
      mreg = mask[(size_t)b * TT + kb0n + lane];
    }

    // ---- S^T = K * Q^T (+ mask-bias ext MFMA). C col = q = ql32 ----
    float16v st0, st1;
#pragma unroll
    for (int r = 0; r < 16; ++r) { st0[r] = 0.f; st1[r] = 0.f; }
    __builtin_amdgcn_s_setprio(1);
    {
      short8 ax0 = *(const short8*)(kxb + ql32 * 16 + hi * 8);
      short8 ax1 = *(const short8*)(kxb + (32 + ql32) * 16 + hi * 8);
      st0 = __builtin_amdgcn_mfma_f32_32x32x16_bf16(ax0, bext, st0, 0, 0, 0);
      st1 = __builtin_amdgcn_mfma_f32_32x32x16_bf16(ax1, bext, st1, 0, 0, 0);
    }
#pragma unroll
    for (int kc8 = 0; kc8 < 8; ++kc8) {
      int csk = ((kc8 * 2 + hi) ^ csw) * 8;
      short8 kf0 = *(const short8*)(ksb + ql32 * 128 + csk);
      short8 kf1 = *(const short8*)(ksb + (32 + ql32) * 128 + csk);
      st0 = __builtin_amdgcn_mfma_f32_32x32x16_bf16(kf0, qf[kc8], st0, 0, 0, 0);
      st1 = __builtin_amdgcn_mfma_f32_32x32x16_bf16(kf1, qf[kc8], st1, 0, 0, 0);
    }
    __builtin_amdgcn_s_setprio(0);

    // ---- softmax core: p = exp2(logit), accumulate denominator ----
    float tsum = 0.f;
#pragma unroll
    for (int r = 0; r < 16; ++r) {
      float p0 = __builtin_amdgcn_exp2f(st0[r]);
      float p1 = __builtin_amdgcn_exp2f(st1[r]);
      st0[r] = p0; st1[r] = p1;
      tsum += p0 + p1;
    }
    l_run += xhalf_add(tsum);

    // ---- P^T B-frags in-register: cvt_pk + permlane32_swap (T12) ----
    short8 pa[4];
#pragma unroll
    for (int kc = 0; kc < 4; ++kc) {
      int a0 = 2 * (kc & 1);
      unsigned x0, x1, y0, y1;
      if (kc < 2) {
        x0 = cvtpk(st0[4 * a0 + 0], st0[4 * a0 + 1]);
        x1 = cvtpk(st0[4 * a0 + 2], st0[4 * a0 + 3]);
        y0 = cvtpk(st0[4 * a0 + 4], st0[4 * a0 + 5]);
        y1 = cvtpk(st0[4 * a0 + 6], st0[4 * a0 + 7]);
      } else {
        x0 = cvtpk(st1[4 * a0 + 0], st1[4 * a0 + 1]);
        x1 = cvtpk(st1[4 * a0 + 2], st1[4 * a0 + 3]);
        y0 = cvtpk(st1[4 * a0 + 4], st1[4 * a0 + 5]);
        y1 = cvtpk(st1[4 * a0 + 6], st1[4 * a0 + 7]);
      }
      asm("v_permlane32_swap_b32 %0, %1" : "+v"(x0), "+v"(y0));
      asm("v_permlane32_swap_b32 %0, %1" : "+v"(x1), "+v"(y1));
      union { unsigned u[4]; short8 s8; } pu;
      pu.u[0] = x0; pu.u[1] = x1; pu.u[2] = y0; pu.u[3] = y1;
      pa[kc] = pu.s8;
    }

    // ---- O^T += V^T * P^T ----
    __builtin_amdgcn_s_setprio(1);
#pragma unroll
    for (int nt = 0; nt < 4; ++nt) {
      int row = nt * 32 + ql32;
#pragma unroll
      for (int kc = 0; kc < 4; ++kc) {
        short8 vf = *(const short8*)(vtb + row * 64 + (((kc * 2 + hi) ^ vsw) * 8));
        o[nt] = __builtin_amdgcn_mfma_f32_32x32x16_bf16(vf, pa[kc], o[nt], 0, 0, 0);
      }
    }
    __builtin_amdgcn_s_setprio(0);

    // ---- stage next tile into the other buffer (loads have landed) ----
    if (kt < 31) {
#pragma unroll
      for (int ps = 0; ps < 2; ++ps) {
        *(short8*)(ksn + kwoff[ps][0]) = va[ps];
        *(short8*)(ksn + kwoff[ps][1]) = vb[ps];
      }
#pragma unroll
      for (int p = 0; p < 4; ++p)
        *(short8*)(vtn + vwoff[p]) = vv[p];
      if (tid < 64) {
        unsigned word = (mreg != 0.f) ? 0u : (unsigned)(unsigned short)negbig;
        *(unsigned*)(kxn + tid * 16) = word;   // elems 0,1 (elem1=0)
      }
    }
  }

  // ---- normalize and write ctx: lane owns q-row, d = nt*32+8a+4hi+{0..3} ----
  float il = 1.0f / l_run;
  short* cp = ctx + ((size_t)(b * TT + qrow)) * DD + h * DKK;
#pragma unroll
  for (int nt = 0; nt < 4; ++nt)
#pragma unroll
    for (int a = 0; a < 4; ++a) {
      short4v sv;
#pragma unroll
      for (int j = 0; j < 4; ++j) sv[j] = f2bf(o[nt][4 * a + j] * il);
      *(short4v*)(cp + nt * 32 + 8 * a + 4 * hi) = sv;
    }
}

extern "C" void kernel_launch(void* const* d_in, const int* in_sizes, int n_in,
                              void* d_out, int out_size, void* d_ws, size_t ws_size,
                              hipStream_t stream) {
  const float* x    = (const float*)d_in[0];
  const float* mask = (const float*)d_in[1];
  const float* Wq   = (const float*)d_in[2];
  const float* Wo   = (const float*)d_in[3];
  char* ws = (char*)d_ws;
  short* xt  = (short*)(ws);                              // 16 MB (reused as qhT)
  short* wqb = (short*)(ws + (size_t)16 * 1024 * 1024);
  short* wob = (short*)(ws + (size_t)18 * 1024 * 1024);
  short* qb  = (short*)(ws + (size_t)20 * 1024 * 1024);
  short* ctx = (short*)(ws + (size_t)36 * 1024 * 1024);
  short* qhT = xt;   // xt dead after k_gemm<0>

  k_xt<<<dim3(64, 32, 4), 256, 0, stream>>>(x, xt);
  k_cast<<<1024, 256, 0, stream>>>(Wq, wqb, 262144);
  k_cast<<<1024, 256, 0, stream>>>(Wo, wob, 262144);
  k_gemm<0><<<dim3(64, 8), 256, 0, stream>>>(xt, wqb, qb);
  k_qt<<<dim3(32, 16, 4), 256, 0, stream>>>(qb, qhT);
  k_attn<<<dim3(16, 32), 256, 0, stream>>>(qb, qhT, mask, ctx);
  k_gemm<1><<<dim3(8, 64), 256, 0, stream>>>(wob, ctx, d_out);
}